// Round 6
// baseline (877.294 us; speedup 1.0000x reference)
//
#include <hip/hip_runtime.h>

#define DIM  128
#define BINS 1024

typedef __attribute__((ext_vector_type(8))) short bf16x8;
typedef __attribute__((ext_vector_type(4))) float f32x4;

#define MFMA(a, b, c) __builtin_amdgcn_mfma_f32_16x16x32_bf16(a, b, c, 0, 0, 0)

#define GLDS(gp, lp) __builtin_amdgcn_global_load_lds(                        \
    (const __attribute__((address_space(1))) void*)(gp),                     \
    (__attribute__((address_space(3))) void*)(lp), 16, 0, 0)

// round-to-nearest-even fp32 -> bf16 bits (no NaN/Inf in this data)
__device__ __forceinline__ unsigned short rne16(float f) {
    unsigned u = __float_as_uint(f);
    unsigned r = u + 0x7FFFu + ((u >> 16) & 1u);
    return (unsigned short)(r >> 16);
}

// branchless top-2 insert, strict > (first-wins with ascending bin order)
__device__ __forceinline__ void ins2(float d, int b,
                                     float& d0, int& b0, float& d1, int& b1) {
    bool c1 = d > d1;
    float nd1 = c1 ? d : d1; int nb1 = c1 ? b : b1;
    bool c0 = nd1 > d0;
    d1 = c0 ? d0 : nd1;  b1 = c0 ? b0 : nb1;
    d0 = c0 ? nd1 : d0;  b0 = c0 ? nb1 : b0;
}

// ---- prep: esq (round-1 1-chain fmaf) + E -> swizzled bf16 hi/lo tables ----
// Full 4-bit XOR swizzle (proven round 5: bank conflicts -> 0)
__global__ __launch_bounds__(256) void vq_prep(
    const float* __restrict__ embed, unsigned short* __restrict__ ehs,
    unsigned short* __restrict__ els, float* __restrict__ esq_g)
{
    int b = blockIdx.x * 256 + threadIdx.x;  // grid exactly BINS/256
    const float* e = embed + (size_t)b * DIM;
    float s = 0.f;
    #pragma unroll
    for (int k = 0; k < DIM; ++k) s = fmaf(e[k], e[k], s);
    esq_g[b] = s;
    #pragma unroll
    for (int c = 0; c < 16; ++c) {          // 16B chunks of the bf16 row
        int slot = c ^ (b & 15);            // XOR-swizzle baked into storage
        #pragma unroll
        for (int j = 0; j < 8; ++j) {
            float f = e[c * 8 + j];
            unsigned short hb = rne16(f);
            float hf = __uint_as_float((unsigned)hb << 16);
            unsigned short lb = rne16(f - hf);
            ehs[b * 128 + slot * 8 + j] = hb;
            els[b * 128 + slot * 8 + j] = lb;
        }
    }
}

// ---- stage A: MFMA approx distances + per-row top-2 candidates ----
// Block: 512 thr = 8 waves; wave w owns rows base+w*32..+31 (two 16-row sets).
// Swapped GEMM: A = E (16 bins x 32 k), B = X^T (32 k x 16 rows).
// D layout (verified): col(lane&15) = x-row, row((lane>>4)*4+reg) = bin.
// 32-bin steps: LDS 36 KB -> 3 blocks/CU (24 waves) at VGPR<=85.
__global__ __launch_bounds__(512, 6) void vq_stage_a(
    const float* __restrict__ x,
    const unsigned short* __restrict__ ehs_g,
    const unsigned short* __restrict__ els_g,
    const float* __restrict__ esq_g,
    float* __restrict__ cand)               // [N][2] candidate bins (as float)
{
    __shared__ unsigned short ehb[2][4096];  // 2 x 8 KB (32 bins x 128 bf16)
    __shared__ unsigned short elb[2][4096];
    __shared__ float esq_lds[BINS];

    const int tid = threadIdx.x;
    const int li  = tid & 15;        // x-row within 16-row set / bin row in tile
    const int g   = (tid >> 4) & 3;  // k-chunk group
    const int w   = tid >> 6;        // wave id

    // ---- load + convert this lane's X chunks (rows li, li+16 of wave tile) ----
    bf16x8 xh[2][4], xl[2][4];
    const size_t rowA = (size_t)blockIdx.x * 256 + w * 32 + li;
    #pragma unroll
    for (int rs = 0; rs < 2; ++rs) {
        const float* xp = x + (rowA + rs * 16) * DIM + g * 8;
        #pragma unroll
        for (int s = 0; s < 4; ++s) {
            float4 v0 = *(const float4*)(xp + s * 32);
            float4 v1 = *(const float4*)(xp + s * 32 + 4);
            float f[8] = {v0.x, v0.y, v0.z, v0.w, v1.x, v1.y, v1.z, v1.w};
            bf16x8 h, lo;
            #pragma unroll
            for (int j = 0; j < 8; ++j) {
                unsigned short hb = rne16(f[j]);
                h[j] = (short)hb;
                float hf = __uint_as_float((unsigned)hb << 16);
                lo[j] = (short)rne16(f[j] - hf);
            }
            xh[rs][s] = h; xl[rs][s] = lo;
        }
    }

    // ---- prologue: stage step 0 (8 KB per table, 16 B/thread) + esq ----
    {
        const char* gE = (const char*)ehs_g;
        const char* gL = (const char*)els_g;
        int o = tid * 16;
        GLDS(gE + o, (char*)&ehb[0][0] + o);
        GLDS(gL + o, (char*)&elb[0][0] + o);
    }
    esq_lds[tid] = esq_g[tid];
    esq_lds[tid + 512] = esq_g[tid + 512];
    asm volatile("s_waitcnt vmcnt(0)" ::: "memory");
    __syncthreads();

    float dA0 = -3.402823466e38f, dA1 = -3.402823466e38f;
    float dB0 = -3.402823466e38f, dB1 = -3.402823466e38f;
    int bA0 = 0, bA1 = 0, bB0 = 0, bB1 = 0;

    // fragment address: row (tl*16+li) at tl*4096+li*256; chunk (g+4s) at
    // slot ((g+4s)^li)*16  (matches vq_prep's c ^ (b&15) since bin&15 == li)
#define LDE(tl_, s_) (*(const bf16x8*)(bE + (tl_) * 4096 + li * 256 + (((g + 4 * (s_)) ^ li) << 4)))
#define LDL(tl_, s_) (*(const bf16x8*)(bL + (tl_) * 4096 + li * 256 + (((g + 4 * (s_)) ^ li) << 4)))

    for (int stp = 0; stp < 32; ++stp) {     // 32 steps x 32 bins
        const int buf = stp & 1;
        if (stp < 31) {                       // prefetch next 32-bin slab
            const char* gE = (const char*)ehs_g + (size_t)(stp + 1) * 8192;
            const char* gL = (const char*)els_g + (size_t)(stp + 1) * 8192;
            int o = tid * 16;
            GLDS(gE + o, (char*)&ehb[buf ^ 1][0] + o);
            GLDS(gL + o, (char*)&elb[buf ^ 1][0] + o);
        }
        const char* bE = (const char*)&ehb[buf][0];
        const char* bL = (const char*)&elb[buf][0];

        // software-pipelined fragment loads across (tl, s)
        bf16x8 ehc = LDE(0, 0), elc = LDL(0, 0);
        #pragma unroll
        for (int tl = 0; tl < 2; ++tl) {
            f32x4 aP0 = {0.f,0.f,0.f,0.f}, aP1 = {0.f,0.f,0.f,0.f};
            f32x4 aQ0 = {0.f,0.f,0.f,0.f}, aQ1 = {0.f,0.f,0.f,0.f};
            #pragma unroll
            for (int s = 0; s < 4; ++s) {
                bf16x8 ehn = ehc, eln = elc;
                int ns = s + 1, ntl = tl;
                if (ns == 4) { ns = 0; ntl = tl + 1; }
                if (ntl < 2) { ehn = LDE(ntl, ns); eln = LDL(ntl, ns); }
                aP0 = MFMA(ehc, xh[0][s], aP0);
                aP1 = MFMA(ehc, xh[1][s], aP1);
                aQ0 = MFMA(elc, xh[0][s], aQ0);
                aQ1 = MFMA(elc, xh[1][s], aQ1);
                aQ0 = MFMA(ehc, xl[0][s], aQ0);
                aQ1 = MFMA(ehc, xl[1][s], aQ1);
                ehc = ehn; elc = eln;
            }
            // fold into top-2; key = 2*dot - esq (monotone in -dist, xsq common)
            const int binb = stp * 32 + tl * 16 + g * 4;
            const f32x4 eq = *(const f32x4*)&esq_lds[binb];
            #pragma unroll
            for (int r = 0; r < 4; ++r) {
                float kA = fmaf(2.f, aP0[r] + aQ0[r], -eq[r]);
                ins2(kA, binb + r, dA0, bA0, dA1, bA1);
                float kB = fmaf(2.f, aP1[r] + aQ1[r], -eq[r]);
                ins2(kB, binb + r, dB0, bB0, dB1, bB1);
            }
        }
        asm volatile("s_waitcnt vmcnt(0)" ::: "memory");
        __syncthreads();
    }
#undef LDE
#undef LDL

    // ---- merge the 4 k-groups (disjoint bin sets, same rows) ----
    #pragma unroll
    for (int mm = 16; mm <= 32; mm <<= 1) {
        float pd0 = __shfl_xor(dA0, mm); int pb0 = __shfl_xor(bA0, mm);
        float pd1 = __shfl_xor(dA1, mm); int pb1 = __shfl_xor(bA1, mm);
        ins2(pd0, pb0, dA0, bA0, dA1, bA1);
        ins2(pd1, pb1, dA0, bA0, dA1, bA1);
        pd0 = __shfl_xor(dB0, mm); pb0 = __shfl_xor(bB0, mm);
        pd1 = __shfl_xor(dB1, mm); pb1 = __shfl_xor(bB1, mm);
        ins2(pd0, pb0, dB0, bB0, dB1, bB1);
        ins2(pd1, pb1, dB0, bB0, dB1, bB1);
    }
    if ((tid & 63) < 16) {
        cand[rowA * 2 + 0] = (float)bA0;
        cand[rowA * 2 + 1] = (float)bA1;
        cand[(rowA + 16) * 2 + 0] = (float)bB0;
        cand[(rowA + 16) * 2 + 1] = (float)bB1;
    }
}

// ---- rescore: exact fp32 (round-1-proven expression) on 2 candidates ----
__global__ __launch_bounds__(256) void vq_rescore(
    const float* __restrict__ x, const float* __restrict__ embed,
    const float* __restrict__ esq_g, const float* __restrict__ cand,
    float* __restrict__ ind_f)
{
    __shared__ float xsm[256 * 129];         // 129-stride: conflict-free rows
    const int tid = threadIdx.x;
    const size_t base = (size_t)blockIdx.x * 256;
    const float4* xg = (const float4*)(x + base * DIM);
    #pragma unroll
    for (int i = 0; i < 32; ++i) {
        int idx = tid + 256 * i;
        int r = idx >> 5, c4 = idx & 31;
        float4 v = xg[idx];
        float* dst = &xsm[r * 129 + c4 * 4];
        dst[0] = v.x; dst[1] = v.y; dst[2] = v.z; dst[3] = v.w;
    }
    __syncthreads();

    const float* xr = &xsm[tid * 129];
    float xsq = 0.f;
    #pragma unroll
    for (int k = 0; k < DIM; ++k) xsq = fmaf(xr[k], xr[k], xsq);

    const size_t row = base + tid;
    int bb[2] = {(int)cand[row * 2], (int)cand[row * 2 + 1]};
    float dd[2];
    #pragma unroll
    for (int c = 0; c < 2; ++c) {
        const float* e = embed + (size_t)bb[c] * DIM;
        float a0 = 0.f, a1 = 0.f, a2 = 0.f, a3 = 0.f;
        #pragma unroll
        for (int k = 0; k < DIM; k += 4) {
            a0 = fmaf(xr[k + 0], e[k + 0], a0);
            a1 = fmaf(xr[k + 1], e[k + 1], a1);
            a2 = fmaf(xr[k + 2], e[k + 2], a2);
            a3 = fmaf(xr[k + 3], e[k + 3], a3);
        }
        float dot = (a0 + a1) + (a2 + a3);
        dd[c] = -(fmaf(-2.f, dot, xsq) + esq_g[bb[c]]);   // round-1 expression
    }
    int wb = bb[0];
    if (dd[1] > dd[0] || (dd[1] == dd[0] && bb[1] < bb[0])) wb = bb[1];
    ind_f[row] = (float)wb;
}

// ---- gather: quantize = embed[ind], coalesced float4 ----
__global__ __launch_bounds__(256) void vq_gather(
    const float* __restrict__ embed,
    const float* __restrict__ ind_f,
    float4* __restrict__ out)
{
    int i   = blockIdx.x * 256 + threadIdx.x;   // over N*DIM/4
    int row = i >> 5;                           // DIM/4 == 32
    int k   = i & 31;
    int b   = (int)ind_f[row];
    out[i] = reinterpret_cast<const float4*>(embed)[b * (DIM / 4) + k];
}

extern "C" void kernel_launch(void* const* d_in, const int* in_sizes, int n_in,
                              void* d_out, int out_size, void* d_ws, size_t ws_size,
                              hipStream_t stream) {
    const float* x     = (const float*)d_in[0];   // [N, 128] fp32
    const float* embed = (const float*)d_in[1];   // [1024, 128] fp32
    float* out = (float*)d_out;

    const int N = in_sizes[0] / DIM;              // 262144
    float* ind_f = out + (size_t)N * DIM;         // output 1 (indices as float)

    // scratch carved out of the quantize region (fully overwritten by gather):
    char* ob = (char*)d_out;
    float* cand = out;                                        // [N][2] floats (2 MB)
    unsigned short* ehs = (unsigned short*)(ob + (32u << 20)); // 256 KB
    unsigned short* els = (unsigned short*)(ob + (34u << 20)); // 256 KB
    float* esq_g        = (float*)(ob + (36u << 20));          // 4 KB

    vq_prep<<<BINS / 256, 256, 0, stream>>>(embed, ehs, els, esq_g);
    vq_stage_a<<<N / 256, 512, 0, stream>>>(x, ehs, els, esq_g, cand);
    vq_rescore<<<N / 256, 256, 0, stream>>>(x, embed, esq_g, cand, ind_f);
    vq_gather<<<(N * (DIM / 4)) / 256, 256, 0, stream>>>(embed, ind_f, (float4*)out);
}

// Round 7
// 330.746 us; speedup vs baseline: 2.6525x; 2.6525x over previous
//
#include <hip/hip_runtime.h>

#define DIM  128
#define BINS 1024

typedef __attribute__((ext_vector_type(8))) short bf16x8;
typedef __attribute__((ext_vector_type(4))) float f32x4;

#define MFMA(a, b, c) __builtin_amdgcn_mfma_f32_16x16x32_bf16(a, b, c, 0, 0, 0)

#define GLDS(gp, lp) __builtin_amdgcn_global_load_lds(                        \
    (const __attribute__((address_space(1))) void*)(gp),                     \
    (__attribute__((address_space(3))) void*)(lp), 16, 0, 0)

// round-to-nearest-even fp32 -> bf16 bits (no NaN/Inf in this data)
__device__ __forceinline__ unsigned short rne16(float f) {
    unsigned u = __float_as_uint(f);
    unsigned r = u + 0x7FFFu + ((u >> 16) & 1u);
    return (unsigned short)(r >> 16);
}

// branchless top-2 insert, strict > (first-wins with ascending bin order)
__device__ __forceinline__ void ins2(float d, int b,
                                     float& d0, int& b0, float& d1, int& b1) {
    bool c1 = d > d1;
    float nd1 = c1 ? d : d1; int nb1 = c1 ? b : b1;
    bool c0 = nd1 > d0;
    d1 = c0 ? d0 : nd1;  b1 = c0 ? b0 : nb1;
    d0 = c0 ? nd1 : d0;  b0 = c0 ? nb1 : b0;
}

// ---- prep: esq (round-1 1-chain fmaf) + E -> swizzled bf16 hi/lo tables ----
// Full 4-bit XOR swizzle (proven round 5: bank conflicts -> 0)
__global__ __launch_bounds__(256) void vq_prep(
    const float* __restrict__ embed, unsigned short* __restrict__ ehs,
    unsigned short* __restrict__ els, float* __restrict__ esq_g)
{
    int b = blockIdx.x * 256 + threadIdx.x;  // grid exactly BINS/256
    const float* e = embed + (size_t)b * DIM;
    float s = 0.f;
    #pragma unroll
    for (int k = 0; k < DIM; ++k) s = fmaf(e[k], e[k], s);
    esq_g[b] = s;
    #pragma unroll
    for (int c = 0; c < 16; ++c) {          // 16B chunks of the bf16 row
        int slot = c ^ (b & 15);            // XOR-swizzle baked into storage
        #pragma unroll
        for (int j = 0; j < 8; ++j) {
            float f = e[c * 8 + j];
            unsigned short hb = rne16(f);
            float hf = __uint_as_float((unsigned)hb << 16);
            unsigned short lb = rne16(f - hf);
            ehs[b * 128 + slot * 8 + j] = hb;
            els[b * 128 + slot * 8 + j] = lb;
        }
    }
}

// ---- stage A: MFMA approx distances + per-row top-2 candidates ----
// Block: 512 thr = 8 waves; wave w owns rows base+w*32..+31 (two 16-row sets).
// Swapped GEMM: A = E (16 bins x 32 k), B = X^T (32 k x 16 rows).
// D layout (verified): col(lane&15) = x-row, row((lane>>4)*4+reg) = bin.
// T3/T4 schedule: triple-buffered 32-bin slabs, counted vmcnt(2), raw
// s_barrier (no vmcnt(0) drain in the loop) -> loads span barriers.
__global__ __launch_bounds__(512, 2) void vq_stage_a(
    const float* __restrict__ x,
    const unsigned short* __restrict__ ehs_g,
    const unsigned short* __restrict__ els_g,
    const float* __restrict__ esq_g,
    float* __restrict__ cand)               // [N][2] candidate bins (as float)
{
    __shared__ unsigned short ehb[3][4096];  // 3 x 8 KB (32 bins x 128 bf16)
    __shared__ unsigned short elb[3][4096];
    __shared__ float esq_lds[BINS];          // 4 KB

    const int tid = threadIdx.x;
    const int li  = tid & 15;        // x-row within 16-row set / bin row in tile
    const int g   = (tid >> 4) & 3;  // k-chunk group
    const int w   = tid >> 6;        // wave id

    // ---- load + convert this lane's X chunks (rows li, li+16 of wave tile) ----
    bf16x8 xh[2][4], xl[2][4];
    const size_t rowA = (size_t)blockIdx.x * 256 + w * 32 + li;
    #pragma unroll
    for (int rs = 0; rs < 2; ++rs) {
        const float* xp = x + (rowA + rs * 16) * DIM + g * 8;
        #pragma unroll
        for (int s = 0; s < 4; ++s) {
            float4 v0 = *(const float4*)(xp + s * 32);
            float4 v1 = *(const float4*)(xp + s * 32 + 4);
            float f[8] = {v0.x, v0.y, v0.z, v0.w, v1.x, v1.y, v1.z, v1.w};
            bf16x8 h, lo;
            #pragma unroll
            for (int j = 0; j < 8; ++j) {
                unsigned short hb = rne16(f[j]);
                h[j] = (short)hb;
                float hf = __uint_as_float((unsigned)hb << 16);
                lo[j] = (short)rne16(f[j] - hf);
            }
            xh[rs][s] = h; xl[rs][s] = lo;
        }
    }

    // ---- prologue: esq GLDS first (oldest -> drained by first vmcnt(2)),
    //      then slabs 0 and 1 ----
    if (tid < 256) GLDS((const char*)esq_g + tid * 16, (char*)esq_lds + tid * 16);
    {
        int o = tid * 16;
        GLDS((const char*)ehs_g + o, (char*)&ehb[0][0] + o);
        GLDS((const char*)els_g + o, (char*)&elb[0][0] + o);
        GLDS((const char*)ehs_g + 8192 + o, (char*)&ehb[1][0] + o);
        GLDS((const char*)els_g + 8192 + o, (char*)&elb[1][0] + o);
    }

    float dA0 = -3.402823466e38f, dA1 = -3.402823466e38f;
    float dB0 = -3.402823466e38f, dB1 = -3.402823466e38f;
    int bA0 = 0, bA1 = 0, bB0 = 0, bB1 = 0;

    // fragment address: row (tl*16+li) at tl*4096+li*256; chunk (g+4s) at
    // slot ((g+4s)^li)*16  (matches vq_prep's c ^ (b&15) since bin&15 == li)
#define LDE(tl_, s_) (*(const bf16x8*)(bE + (tl_) * 4096 + li * 256 + (((g + 4 * (s_)) ^ li) << 4)))
#define LDL(tl_, s_) (*(const bf16x8*)(bL + (tl_) * 4096 + li * 256 + (((g + 4 * (s_)) ^ li) << 4)))

    for (int stp = 0; stp < 32; ++stp) {     // 32 steps x 32 bins
        // wait own share of slab stp (leave stp+1/stp+2 in flight), then sync.
        if (stp < 31) asm volatile("s_waitcnt vmcnt(2)" ::: "memory");
        else          asm volatile("s_waitcnt vmcnt(0)" ::: "memory");
        __builtin_amdgcn_s_barrier();
        // issue slab stp+2 into buf[(stp+2)%3] (read of that buf finished
        // by all waves before the barrier above)
        if (stp + 2 < 32) {
            const char* gE = (const char*)ehs_g + (size_t)(stp + 2) * 8192;
            const char* gL = (const char*)els_g + (size_t)(stp + 2) * 8192;
            int o = tid * 16;
            GLDS(gE + o, (char*)&ehb[(stp + 2) % 3][0] + o);
            GLDS(gL + o, (char*)&elb[(stp + 2) % 3][0] + o);
        }
        const char* bE = (const char*)&ehb[stp % 3][0];
        const char* bL = (const char*)&elb[stp % 3][0];

        // software-pipelined fragment loads across (tl, s)
        bf16x8 ehc = LDE(0, 0), elc = LDL(0, 0);
        #pragma unroll
        for (int tl = 0; tl < 2; ++tl) {
            f32x4 aP0 = {0.f,0.f,0.f,0.f}, aP1 = {0.f,0.f,0.f,0.f};
            f32x4 aQ0 = {0.f,0.f,0.f,0.f}, aQ1 = {0.f,0.f,0.f,0.f};
            #pragma unroll
            for (int s = 0; s < 4; ++s) {
                bf16x8 ehn = ehc, eln = elc;
                int ns = s + 1, ntl = tl;
                if (ns == 4) { ns = 0; ntl = tl + 1; }
                if (ntl < 2) { ehn = LDE(ntl, ns); eln = LDL(ntl, ns); }
                aP0 = MFMA(ehc, xh[0][s], aP0);
                aP1 = MFMA(ehc, xh[1][s], aP1);
                aQ0 = MFMA(elc, xh[0][s], aQ0);
                aQ1 = MFMA(elc, xh[1][s], aQ1);
                aQ0 = MFMA(ehc, xl[0][s], aQ0);
                aQ1 = MFMA(ehc, xl[1][s], aQ1);
                ehc = ehn; elc = eln;
            }
            // fold into top-2; key = 2*dot - esq (monotone in -dist, xsq common)
            const int binb = stp * 32 + tl * 16 + g * 4;
            const f32x4 eq = *(const f32x4*)&esq_lds[binb];
            #pragma unroll
            for (int r = 0; r < 4; ++r) {
                float kA = fmaf(2.f, aP0[r] + aQ0[r], -eq[r]);
                ins2(kA, binb + r, dA0, bA0, dA1, bA1);
                float kB = fmaf(2.f, aP1[r] + aQ1[r], -eq[r]);
                ins2(kB, binb + r, dB0, bB0, dB1, bB1);
            }
        }
        // no trailing drain: next iteration's vmcnt(2) + barrier handle it
    }
#undef LDE
#undef LDL

    // ---- merge the 4 k-groups (disjoint bin sets, same rows) ----
    #pragma unroll
    for (int mm = 16; mm <= 32; mm <<= 1) {
        float pd0 = __shfl_xor(dA0, mm); int pb0 = __shfl_xor(bA0, mm);
        float pd1 = __shfl_xor(dA1, mm); int pb1 = __shfl_xor(bA1, mm);
        ins2(pd0, pb0, dA0, bA0, dA1, bA1);
        ins2(pd1, pb1, dA0, bA0, dA1, bA1);
        pd0 = __shfl_xor(dB0, mm); pb0 = __shfl_xor(bB0, mm);
        pd1 = __shfl_xor(dB1, mm); pb1 = __shfl_xor(bB1, mm);
        ins2(pd0, pb0, dB0, bB0, dB1, bB1);
        ins2(pd1, pb1, dB0, bB0, dB1, bB1);
    }
    if ((tid & 63) < 16) {
        cand[rowA * 2 + 0] = (float)bA0;
        cand[rowA * 2 + 1] = (float)bA1;
        cand[(rowA + 16) * 2 + 0] = (float)bB0;
        cand[(rowA + 16) * 2 + 1] = (float)bB1;
    }
}

// ---- rescore: exact fp32 (round-1-proven expression) on 2 candidates ----
__global__ __launch_bounds__(256) void vq_rescore(
    const float* __restrict__ x, const float* __restrict__ embed,
    const float* __restrict__ esq_g, const float* __restrict__ cand,
    float* __restrict__ ind_f)
{
    __shared__ float xsm[256 * 129];         // 129-stride: conflict-free rows
    const int tid = threadIdx.x;
    const size_t base = (size_t)blockIdx.x * 256;
    const float4* xg = (const float4*)(x + base * DIM);
    #pragma unroll
    for (int i = 0; i < 32; ++i) {
        int idx = tid + 256 * i;
        int r = idx >> 5, c4 = idx & 31;
        float4 v = xg[idx];
        float* dst = &xsm[r * 129 + c4 * 4];
        dst[0] = v.x; dst[1] = v.y; dst[2] = v.z; dst[3] = v.w;
    }
    __syncthreads();

    const float* xr = &xsm[tid * 129];
    float xsq = 0.f;
    #pragma unroll
    for (int k = 0; k < DIM; ++k) xsq = fmaf(xr[k], xr[k], xsq);

    const size_t row = base + tid;
    int bb[2] = {(int)cand[row * 2], (int)cand[row * 2 + 1]};
    float dd[2];
    #pragma unroll
    for (int c = 0; c < 2; ++c) {
        const float* e = embed + (size_t)bb[c] * DIM;
        float a0 = 0.f, a1 = 0.f, a2 = 0.f, a3 = 0.f;
        #pragma unroll
        for (int k = 0; k < DIM; k += 4) {
            a0 = fmaf(xr[k + 0], e[k + 0], a0);
            a1 = fmaf(xr[k + 1], e[k + 1], a1);
            a2 = fmaf(xr[k + 2], e[k + 2], a2);
            a3 = fmaf(xr[k + 3], e[k + 3], a3);
        }
        float dot = (a0 + a1) + (a2 + a3);
        dd[c] = -(fmaf(-2.f, dot, xsq) + esq_g[bb[c]]);   // round-1 expression
    }
    int wb = bb[0];
    if (dd[1] > dd[0] || (dd[1] == dd[0] && bb[1] < bb[0])) wb = bb[1];
    ind_f[row] = (float)wb;
}

// ---- gather: quantize = embed[ind], coalesced float4 ----
__global__ __launch_bounds__(256) void vq_gather(
    const float* __restrict__ embed,
    const float* __restrict__ ind_f,
    float4* __restrict__ out)
{
    int i   = blockIdx.x * 256 + threadIdx.x;   // over N*DIM/4
    int row = i >> 5;                           // DIM/4 == 32
    int k   = i & 31;
    int b   = (int)ind_f[row];
    out[i] = reinterpret_cast<const float4*>(embed)[b * (DIM / 4) + k];
}

extern "C" void kernel_launch(void* const* d_in, const int* in_sizes, int n_in,
                              void* d_out, int out_size, void* d_ws, size_t ws_size,
                              hipStream_t stream) {
    const float* x     = (const float*)d_in[0];   // [N, 128] fp32
    const float* embed = (const float*)d_in[1];   // [1024, 128] fp32
    float* out = (float*)d_out;

    const int N = in_sizes[0] / DIM;              // 262144
    float* ind_f = out + (size_t)N * DIM;         // output 1 (indices as float)

    // scratch carved out of the quantize region (fully overwritten by gather):
    char* ob = (char*)d_out;
    float* cand = out;                                        // [N][2] floats (2 MB)
    unsigned short* ehs = (unsigned short*)(ob + (32u << 20)); // 256 KB
    unsigned short* els = (unsigned short*)(ob + (34u << 20)); // 256 KB
    float* esq_g        = (float*)(ob + (36u << 20));          // 4 KB

    vq_prep<<<BINS / 256, 256, 0, stream>>>(embed, ehs, els, esq_g);
    vq_stage_a<<<N / 256, 512, 0, stream>>>(x, ehs, els, esq_g, cand);
    vq_rescore<<<N / 256, 256, 0, stream>>>(x, embed, esq_g, cand, ind_f);
    vq_gather<<<(N * (DIM / 4)) / 256, 256, 0, stream>>>(embed, ind_f, (float4*)out);
}